// Round 9
// baseline (1596.753 us; speedup 1.0000x reference)
//
#include <hip/hip_runtime.h>
#include <hip/hip_bf16.h>
#include <math.h>

typedef unsigned int u32;
typedef unsigned short u16;
typedef __attribute__((ext_vector_type(8))) short bf16x8;
typedef __attribute__((ext_vector_type(4))) float f32x4;

#define NBATCH 1024
#define TT 128
#define NB 16
#define NBLK 64
#define OUTD 32

// ---- ws fragment offsets (u16 indices); gW3 stored with permuted cols n*64+l ----
#define F_DW1 0
#define F_GW1 8192
#define F_DW2 16384
#define F_GW2 32768
#define F_DW3 49152
#define F_GW3 57344
#define F_RO1 188416
#define F_RO2 196608
#define U16_END 200704
#define FW_EMB 0
#define FW_W0D 4096
#define FW_W0G 4224

// ---- LDS map: u16 offsets ----
#define LW2   0        // [2][16384] W2 fragments (both nets), 65536 B
#define ZHI   32768    // [16][72]
#define ZLO   33920
#define YBHI  35072
#define YBLO  36224
#define H1HI  37376    // [2][16][136]
#define H1LO  41728
#define H2HI  46080
#define H2LO  50432
#define HROHI 54784    // [16][136]
#define HROLO 56960
// ---- f32 offsets (into sm) ----
#define FUP   29568    // [4][16][64]
#define FVP   33664    // [4][16][64]
#define FF1   37760    // [16][68]
#define FDW   38848    // [16][16][2]
#define FW0D  39360
#define FW0G  39488
#define FB1D  39616
#define FB1G  39744
#define FB2D  39872
#define FB2G  40000
#define FB3D  40128    // [64]
#define FRB1  40192    // [128]
#define FRB2  40320    // [32]
#define FTS   40352    // [128]
#define LDS_FLOATS 40480   // 161920 B

__device__ __forceinline__ float lipswish(float x) {
  return 0.909f * x / (1.0f + expf(-x));
}
__device__ __forceinline__ u32 bf16r(float x) {
  u32 u = __float_as_uint(x);
  return ((u + 0x7fffu + ((u >> 16) & 1u)) >> 16) & 0xffffu;
}
__device__ __forceinline__ void splitw(float x, u16& h, u16& l) {
  const u32 hb = bf16r(x);
  h = (u16)hb;
  l = (u16)bf16r(x - __uint_as_float(hb << 16));
}

// ---------------- prep: weight-norm + bf16 fragment pack (gW3 col-permuted) ----------------
__global__ void prep_kernel(const float* dr_v1, const float* dr_g1,
                            const float* dr_v2, const float* dr_g2,
                            const float* dr_v3, const float* dr_g3,
                            const float* di_v1, const float* di_g1,
                            const float* di_v2, const float* di_g2,
                            const float* di_v3, const float* di_g3,
                            const float* emb_W, const float* ro_W1, const float* ro_W2,
                            float* ws) {
  __shared__ float sred[2];
  u16* wsu = (u16*)ws;
  float* wsf = (float*)(wsu + U16_END);
  const int mat = blockIdx.y;
  const int row = blockIdx.x;
  const int i = threadIdx.x;
  const float* v = nullptr; const float* g = nullptr;
  int rows = 0, len = 0, O = 0; long F = -1; int l1 = 0; int w0 = 0;
  switch (mat) {
    case 0: v = dr_v1; g = dr_g1; rows = 128;  len = 65;  O = 128;  F = F_DW1; l1 = 1; w0 = FW_W0D; break;
    case 1: v = dr_v2; g = dr_g2; rows = 128;  len = 128; O = 128;  F = F_DW2; break;
    case 2: v = dr_v3; g = dr_g3; rows = 64;   len = 128; O = 64;   F = F_DW3; break;
    case 3: v = di_v1; g = di_g1; rows = 128;  len = 65;  O = 128;  F = F_GW1; l1 = 1; w0 = FW_W0G; break;
    case 4: v = di_v2; g = di_g2; rows = 128;  len = 128; O = 128;  F = F_GW2; break;
    case 5: v = di_v3; g = di_g3; rows = 1024; len = 128; O = 1024; F = F_GW3; break;
    case 6: v = emb_W; g = nullptr; rows = 64;  len = 64;  break;
    case 7: v = ro_W1; g = nullptr; rows = 128; len = 64;  O = 128; F = F_RO1; break;
    case 8: v = ro_W2; g = nullptr; rows = 32;  len = 128; O = 32;  F = F_RO2; break;
  }
  if (row >= rows) return;
  const float x = (i < len) ? v[(size_t)row * len + i] : 0.0f;
  float scale = 1.0f;
  if (g != nullptr) {
    float ss = x * x;
    #pragma unroll
    for (int d = 1; d < 64; d <<= 1) ss += __shfl_xor(ss, d);
    if ((i & 63) == 0) sred[i >> 6] = ss;
    __syncthreads();
    scale = g[row] / sqrtf(sred[0] + sred[1]);
  }
  const float xs = x * scale;
  if (mat == 6) {
    if (i < len) wsf[FW_EMB + i * 64 + row] = xs;
    return;
  }
  int ro = row;
  if (mat == 5) ro = ((row & 15) << 6) | (row >> 4);   // col permute: n*64 + l
  if (l1) {
    if (i == 0) wsf[w0 + row] = xs;
    if (i >= 1 && i < len) {
      const int kk = i - 1;
      wsu[F + ((size_t)((kk >> 3) * O + ro)) * 8 + (kk & 7)] = (u16)bf16r(xs);
    }
  } else if (i < len) {
    wsu[F + ((size_t)((i >> 3) * O + ro)) * 8 + (i & 7)] = (u16)bf16r(xs);
  }
}

__device__ __forceinline__ f32x4 mfma2(bf16x8 hi, bf16x8 lo, bf16x8 b, f32x4 acc) {
  acc = __builtin_amdgcn_mfma_f32_16x16x32_bf16(hi, b, acc, 0, 0, 0);
  acc = __builtin_amdgcn_mfma_f32_16x16x32_bf16(lo, b, acc, 0, 0, 0);
  return acc;
}
__device__ __forceinline__ bf16x8 ldfrag(const u16* p) { return *(const bf16x8*)p; }

// ---------------- main persistent kernel: 64 blocks x 1024 threads (16 waves), 16 rows ----------------
__global__ void __launch_bounds__(1024, 4)
sde_main(const float* __restrict__ init_noise, const float* __restrict__ bm,
         const float* __restrict__ ts_g, const int* __restrict__ p_steps,
         const int* __restrict__ p_mult, const float* __restrict__ emb_b,
         const float* __restrict__ dr_b1, const float* __restrict__ dr_b2, const float* __restrict__ dr_b3,
         const float* __restrict__ di_b1, const float* __restrict__ di_b2, const float* __restrict__ di_b3,
         const float* __restrict__ ro_b1, const float* __restrict__ ro_b2,
         const float* __restrict__ ws, float* __restrict__ out)
{
  extern __shared__ float sm[];
  u16* lu = (u16*)sm;

  const int t = threadIdx.x;
  const int b0 = blockIdx.x * NB;
  const u16* __restrict__ wsu = (const u16*)ws;
  const float* __restrict__ wsf = (const float*)(wsu + U16_END);
  const int steps = p_steps[0], mult = p_mult[0];

  // ---- stage W2 fragments into LDS (65536 B, contiguous from F_DW2) ----
  {
    float4* dst = (float4*)lu;
    const float4* src = (const float4*)(wsu + F_DW2);
    #pragma unroll 4
    for (int i = t; i < 4096; i += 1024) dst[i] = src[i];
  }
  // ---- stage constants ----
  {
    if (t < 128) { sm[FTS + t] = ts_g[t]; sm[FW0D + t] = wsf[FW_W0D + t]; sm[FW0G + t] = wsf[FW_W0G + t]; }
    else if (t < 256) { const int i = t - 128; sm[FB1D + i] = dr_b1[i]; sm[FB1G + i] = di_b1[i]; }
    else if (t < 384) { const int i = t - 256; sm[FB2D + i] = dr_b2[i]; sm[FB2G + i] = di_b2[i]; }
    else if (t < 512) { sm[FRB1 + t - 384] = ro_b1[t - 384]; }
    else if (t < 576) { sm[FB3D + t - 512] = dr_b3[t - 512]; }
    else if (t < 608) { sm[FRB2 + t - 576] = ro_b2[t - 576]; }
    if (t < 256) { float2 zz; zz.x = 0.f; zz.y = 0.f;
                   *(float2*)&sm[FDW + (t >> 4) * 32 + (t & 15) * 2] = zz; }
  }

  // ---- init: y0 = init_noise @ embT + emb_b; 1 state element per thread ----
  const int r_own = t >> 6;
  const int o_own = t & 63;
  float y_r, z_r, f_r = 0.f, v_r = 0.f;
  {
    const float* __restrict__ inr = init_noise + (size_t)(b0 + r_own) * 64;
    float a = emb_b[o_own];
    #pragma unroll 8
    for (int i = 0; i < 64; ++i) a = fmaf(inr[i], wsf[FW_EMB + i * 64 + o_own], a);
    y_r = a; z_r = a;
    u16 hh, ll; splitw(a, hh, ll);
    lu[ZHI + r_own * 72 + o_own] = hh;
    lu[ZLO + r_own * 72 + o_own] = ll;
    lu[YBHI + r_own * 72 + o_own] = hh;
    lu[YBLO + r_own * 72 + o_own] = ll;
  }

  const int w = t >> 6;          // wave 0..15
  const int lane = t & 63;
  const int g = lane >> 4;       // k-octet group
  const int c = lane & 15;       // A-row / col index
  const int netw = w >> 3;       // L1/L2: waves 0-7 drift, 8-15 diffusion
  const int nt = w & 7;
  const int col1 = nt * 16 + c;  // this wave's N-column for L1/L2
  const int nq = w >> 2;         // gW3 noise quarter (0..3)
  const int lt = w & 3;          // gW3 latent tile (0..3)

  // small per-wave weight fragments (loaded once; compiler may reload — cheap)
  bf16x8 rw1[2];
  #pragma unroll
  for (int kt = 0; kt < 2; ++kt)
    rw1[kt] = ldfrag(wsu + (netw ? F_GW1 : F_DW1) + ((size_t)((kt * 4 + g) * 128 + col1)) * 8);
  bf16x8 rro1[2];
  if (w >= 8) {
    #pragma unroll
    for (int kt = 0; kt < 2; ++kt)
      rro1[kt] = ldfrag(wsu + F_RO1 + ((size_t)((kt * 4 + g) * 128 + (w - 8) * 16 + c)) * 8);
  }
  bf16x8 rd3[4];
  if (w < 4) {
    #pragma unroll
    for (int kt = 0; kt < 4; ++kt)
      rd3[kt] = ldfrag(wsu + F_DW3 + ((size_t)((kt * 4 + g) * 64 + w * 16 + c)) * 8);
  }
  bf16x8 rro2[4];
  if (w < 2) {
    #pragma unroll
    for (int kt = 0; kt < 4; ++kt)
      rro2[kt] = ldfrag(wsu + F_RO2 + ((size_t)((kt * 4 + g) * 32 + w * 16 + c)) * 8);
  }

  __syncthreads();

  #pragma unroll 1
  for (int k = 0; k < TT; ++k) {
    const float tval = sm[FTS + k];

    // ==== P1: L1 both nets (1 tile/wave) + ro1(y[k-1]) on waves 8-15 + noise rotate ====
    {
      bf16x8 zh[2], zl[2];
      #pragma unroll
      for (int kt = 0; kt < 2; ++kt) {
        zh[kt] = ldfrag(lu + ZHI + c * 72 + kt * 32 + g * 8);
        zl[kt] = ldfrag(lu + ZLO + c * 72 + kt * 32 + g * 8);
      }
      const float ci = netw ? fmaf(tval, sm[FW0G + col1], sm[FB1G + col1])
                            : fmaf(tval, sm[FW0D + col1], sm[FB1D + col1]);
      f32x4 acc = {ci, ci, ci, ci};
      #pragma unroll
      for (int kt = 0; kt < 2; ++kt) acc = mfma2(zh[kt], zl[kt], rw1[kt], acc);
      #pragma unroll
      for (int j = 0; j < 4; ++j) {
        u16 hh, ll; splitw(lipswish(acc[j]), hh, ll);
        lu[H1HI + netw * 2176 + (g * 4 + j) * 136 + col1] = hh;
        lu[H1LO + netw * 2176 + (g * 4 + j) * 136 + col1] = ll;
      }
      if (w >= 8 && k > 0) {     // readout stage 1, token k-1
        bf16x8 yh[2], yl[2];
        #pragma unroll
        for (int kt = 0; kt < 2; ++kt) {
          yh[kt] = ldfrag(lu + YBHI + c * 72 + kt * 32 + g * 8);
          yl[kt] = ldfrag(lu + YBLO + c * 72 + kt * 32 + g * 8);
        }
        const int colr = (w - 8) * 16 + c;
        const float cr = sm[FRB1 + colr];
        f32x4 ar = {cr, cr, cr, cr};
        #pragma unroll
        for (int kt = 0; kt < 2; ++kt) ar = mfma2(yh[kt], yl[kt], rro1[kt], ar);
        #pragma unroll
        for (int j = 0; j < 4; ++j) {
          u16 hh, ll; splitw(lipswish(ar[j]), hh, ll);
          lu[HROHI + (g * 4 + j) * 136 + colr] = hh;
          lu[HROLO + (g * 4 + j) * 136 + colr] = ll;
        }
      }
      if (t < 256) {             // rotate noise: dwi = old dwn; dwn = dw_k
        const int rr = t >> 4, nn = t & 15;
        const float old = sm[FDW + rr * 32 + nn * 2 + 1];
        float nv = 0.f;
        if (k < TT - 1)
          nv = bm[((size_t)k * NBATCH + b0 + rr) * 16 + nn] * sqrtf(sm[FTS + k + 1] - tval);
        float2 wv; wv.x = old; wv.y = nv;
        *(float2*)&sm[FDW + rr * 32 + nn * 2] = wv;
      }
    }
    __syncthreads();

    // ==== P2: L2 both nets (1 tile/wave, B from LDS) + ro2 -> out (waves 0-1) ====
    {
      bf16x8 ah[4], al[4];
      #pragma unroll
      for (int kt = 0; kt < 4; ++kt) {
        ah[kt] = ldfrag(lu + H1HI + netw * 2176 + c * 136 + kt * 32 + g * 8);
        al[kt] = ldfrag(lu + H1LO + netw * 2176 + c * 136 + kt * 32 + g * 8);
      }
      const float ci = netw ? sm[FB2G + col1] : sm[FB2D + col1];
      f32x4 acc = {ci, ci, ci, ci};
      #pragma unroll
      for (int kt = 0; kt < 4; ++kt) {
        const bf16x8 b = ldfrag(lu + LW2 + netw * 16384 + ((kt * 4 + g) * 128 + col1) * 8);
        acc = mfma2(ah[kt], al[kt], b, acc);
      }
      #pragma unroll
      for (int j = 0; j < 4; ++j) {
        u16 hh, ll; splitw(lipswish(acc[j]), hh, ll);
        lu[H2HI + netw * 2176 + (g * 4 + j) * 136 + col1] = hh;
        lu[H2LO + netw * 2176 + (g * 4 + j) * 136 + col1] = ll;
      }
      if (w < 2 && k > 0) {      // readout stage 2, token k-1
        bf16x8 hh4[4], hl4[4];
        #pragma unroll
        for (int kt = 0; kt < 4; ++kt) {
          hh4[kt] = ldfrag(lu + HROHI + c * 136 + kt * 32 + g * 8);
          hl4[kt] = ldfrag(lu + HROLO + c * 136 + kt * 32 + g * 8);
        }
        const int col = w * 16 + c;
        const float cr = sm[FRB2 + col];
        f32x4 ar = {cr, cr, cr, cr};
        #pragma unroll
        for (int kt = 0; kt < 4; ++kt) ar = mfma2(hh4[kt], hl4[kt], rro2[kt], ar);
        const int tg = k - 1;
        const int matched = (mult > 0 && (tg % mult) == 0) ? (tg / mult) : -1;
        #pragma unroll
        for (int j = 0; j < 4; ++j) {
          const int m = g * 4 + j;
          out[((size_t)(b0 + m) * TT + tg) * OUTD + col] = ar[j];
          if (matched >= 0 && matched < steps)
            out[(size_t)NBATCH * TT * OUTD + ((size_t)(b0 + m) * steps + matched) * OUTD + col] = ar[j];
        }
      }
    }
    __syncthreads();

    // ==== P3: dW3 (waves 0-3) + gW3 streamed (4 tiles/wave) with in-flight contraction ====
    {
      if (w < 4) {
        bf16x8 dh[4], dl[4];
        #pragma unroll
        for (int kt = 0; kt < 4; ++kt) {
          dh[kt] = ldfrag(lu + H2HI + c * 136 + kt * 32 + g * 8);
          dl[kt] = ldfrag(lu + H2LO + c * 136 + kt * 32 + g * 8);
        }
        const int col = w * 16 + c;
        const float ci = sm[FB3D + col];
        f32x4 acc = {ci, ci, ci, ci};
        #pragma unroll
        for (int kt = 0; kt < 4; ++kt) acc = mfma2(dh[kt], dl[kt], rd3[kt], acc);
        #pragma unroll
        for (int j = 0; j < 4; ++j) sm[FF1 + (g * 4 + j) * 68 + col] = acc[j];
      }
      bf16x8 gh[4], gl[4];
      #pragma unroll
      for (int kt = 0; kt < 4; ++kt) {
        gh[kt] = ldfrag(lu + H2HI + 2176 + c * 136 + kt * 32 + g * 8);
        gl[kt] = ldfrag(lu + H2LO + 2176 + c * 136 + kt * 32 + g * 8);
      }
      float ua[4] = {0.f, 0.f, 0.f, 0.f}, va[4] = {0.f, 0.f, 0.f, 0.f};
      #pragma unroll
      for (int a = 0; a < 4; ++a) {
        const int n = nq * 4 + a;
        const int colb = n * 64 + lt * 16 + c;
        const float ci = di_b3[(lt * 16 + c) * 16 + n];     // permuted bias
        bf16x8 bfr[4];
        #pragma unroll
        for (int kt = 0; kt < 4; ++kt)
          bfr[kt] = ldfrag(wsu + F_GW3 + ((size_t)((kt * 4 + g) * 1024 + colb)) * 8);
        f32x4 acc = {ci, ci, ci, ci};
        #pragma unroll
        for (int kt = 0; kt < 4; ++kt) acc = mfma2(gh[kt], gl[kt], bfr[kt], acc);
        #pragma unroll
        for (int j = 0; j < 4; ++j) {
          const float2 dw = *(const float2*)&sm[FDW + (g * 4 + j) * 32 + n * 2];
          ua[j] = fmaf(acc[j], dw.x, ua[j]);
          va[j] = fmaf(acc[j], dw.y, va[j]);
        }
      }
      #pragma unroll
      for (int j = 0; j < 4; ++j) {
        sm[FUP + nq * 1024 + (g * 4 + j) * 64 + lt * 16 + c] = ua[j];
        sm[FVP + nq * 1024 + (g * 4 + j) * 64 + lt * 16 + c] = va[j];
      }
    }
    __syncthreads();

    // ==== P4: Heun update, one element per thread ====
    {
      const float f1 = sm[FF1 + r_own * 68 + o_own];
      float u1 = 0.f, v1 = 0.f;
      #pragma unroll
      for (int q = 0; q < 4; ++q) {
        u1 += sm[FUP + q * 1024 + r_own * 64 + o_own];
        v1 += sm[FVP + q * 1024 + r_own * 64 + o_own];
      }
      const float dti = (k > 0) ? (tval - sm[FTS + k - 1]) : 0.f;
      const float dtn = (k < TT - 1) ? (sm[FTS + k + 1] - tval) : 0.f;
      y_r += 0.5f * (f_r + f1) * dti + 0.5f * (v_r + u1);
      z_r = 2.f * y_r - z_r + f1 * dtn + v1;
      f_r = f1; v_r = v1;
      u16 hh, ll;
      splitw(z_r, hh, ll);
      lu[ZHI + r_own * 72 + o_own] = hh;
      lu[ZLO + r_own * 72 + o_own] = ll;
      splitw(y_r, hh, ll);
      lu[YBHI + r_own * 72 + o_own] = hh;
      lu[YBLO + r_own * 72 + o_own] = ll;
    }
    __syncthreads();
  }

  // ==== tail: readout of token TT-1 ====
  if (w >= 8) {
    bf16x8 yh[2], yl[2];
    #pragma unroll
    for (int kt = 0; kt < 2; ++kt) {
      yh[kt] = ldfrag(lu + YBHI + c * 72 + kt * 32 + g * 8);
      yl[kt] = ldfrag(lu + YBLO + c * 72 + kt * 32 + g * 8);
    }
    const int colr = (w - 8) * 16 + c;
    const float cr = sm[FRB1 + colr];
    f32x4 ar = {cr, cr, cr, cr};
    #pragma unroll
    for (int kt = 0; kt < 2; ++kt) ar = mfma2(yh[kt], yl[kt], rro1[kt], ar);
    #pragma unroll
    for (int j = 0; j < 4; ++j) {
      u16 hh, ll; splitw(lipswish(ar[j]), hh, ll);
      lu[HROHI + (g * 4 + j) * 136 + colr] = hh;
      lu[HROLO + (g * 4 + j) * 136 + colr] = ll;
    }
  }
  __syncthreads();
  if (w < 2) {
    bf16x8 hh4[4], hl4[4];
    #pragma unroll
    for (int kt = 0; kt < 4; ++kt) {
      hh4[kt] = ldfrag(lu + HROHI + c * 136 + kt * 32 + g * 8);
      hl4[kt] = ldfrag(lu + HROLO + c * 136 + kt * 32 + g * 8);
    }
    const int col = w * 16 + c;
    const float cr = sm[FRB2 + col];
    f32x4 ar = {cr, cr, cr, cr};
    #pragma unroll
    for (int kt = 0; kt < 4; ++kt) ar = mfma2(hh4[kt], hl4[kt], rro2[kt], ar);
    const int tg = TT - 1;
    const int matched = (mult > 0 && (tg % mult) == 0) ? (tg / mult) : -1;
    #pragma unroll
    for (int j = 0; j < 4; ++j) {
      const int m = g * 4 + j;
      out[((size_t)(b0 + m) * TT + tg) * OUTD + col] = ar[j];
      if (matched >= 0 && matched < steps)
        out[(size_t)NBATCH * TT * OUTD + ((size_t)(b0 + m) * steps + matched) * OUTD + col] = ar[j];
    }
  }
}

extern "C" void kernel_launch(void* const* d_in, const int* in_sizes, int n_in,
                              void* d_out, int out_size, void* d_ws, size_t ws_size,
                              hipStream_t stream) {
  (void)in_sizes; (void)n_in; (void)out_size; (void)ws_size;
  const float* init_noise = (const float*)d_in[0];
  const float* bm_noise   = (const float*)d_in[1];
  const float* ts         = (const float*)d_in[2];
  const int*   p_steps    = (const int*)d_in[3];
  const int*   p_mult     = (const int*)d_in[4];
  const float* emb_W = (const float*)d_in[5];
  const float* emb_b = (const float*)d_in[6];
  const float* dr_v1 = (const float*)d_in[7];
  const float* dr_g1 = (const float*)d_in[8];
  const float* dr_b1 = (const float*)d_in[9];
  const float* dr_v2 = (const float*)d_in[10];
  const float* dr_g2 = (const float*)d_in[11];
  const float* dr_b2 = (const float*)d_in[12];
  const float* dr_v3 = (const float*)d_in[13];
  const float* dr_g3 = (const float*)d_in[14];
  const float* dr_b3 = (const float*)d_in[15];
  const float* di_v1 = (const float*)d_in[16];
  const float* di_g1 = (const float*)d_in[17];
  const float* di_b1 = (const float*)d_in[18];
  const float* di_v2 = (const float*)d_in[19];
  const float* di_g2 = (const float*)d_in[20];
  const float* di_b2 = (const float*)d_in[21];
  const float* di_v3 = (const float*)d_in[22];
  const float* di_g3 = (const float*)d_in[23];
  const float* di_b3 = (const float*)d_in[24];
  const float* ro_W1 = (const float*)d_in[25];
  const float* ro_b1 = (const float*)d_in[26];
  const float* ro_W2 = (const float*)d_in[27];
  const float* ro_b2 = (const float*)d_in[28];
  float* ws = (float*)d_ws;
  float* out = (float*)d_out;

  (void)hipFuncSetAttribute((const void*)sde_main,
                            hipFuncAttributeMaxDynamicSharedMemorySize, 160 * 1024);

  prep_kernel<<<dim3(1024, 9), 128, 0, stream>>>(
      dr_v1, dr_g1, dr_v2, dr_g2, dr_v3, dr_g3,
      di_v1, di_g1, di_v2, di_g2, di_v3, di_g3,
      emb_W, ro_W1, ro_W2, ws);

  sde_main<<<NBLK, 1024, LDS_FLOATS * 4, stream>>>(
      init_noise, bm_noise, ts, p_steps, p_mult,
      emb_b, dr_b1, dr_b2, dr_b3, di_b1, di_b2, di_b3,
      ro_b1, ro_b2, ws, out);
}

// Round 10
// 1572.428 us; speedup vs baseline: 1.0155x; 1.0155x over previous
//
#include <hip/hip_runtime.h>
#include <hip/hip_bf16.h>
#include <math.h>

typedef unsigned int u32;
typedef unsigned short u16;
typedef __attribute__((ext_vector_type(8))) short bf16x8;
typedef __attribute__((ext_vector_type(4))) float f32x4;

#define NBATCH 1024
#define TT 128
#define NB 16
#define NBLK 64
#define OUTD 32

// ---- ws fragment offsets (u16 indices); gW3 stored with permuted cols n*64+l ----
#define F_DW1 0
#define F_GW1 8192
#define F_DW2 16384
#define F_GW2 32768
#define F_DW3 49152
#define F_GW3 57344
#define F_RO1 188416
#define F_RO2 196608
#define U16_END 200704
#define FW_EMB 0
#define FW_W0D 4096
#define FW_W0G 4224

// ---- LDS map: u16 offsets ----
#define LW2   0        // [2][16384] W2 fragments (both nets), 65536 B
#define ZHI   32768    // [16][72]
#define ZLO   33920
#define YBHI  35072
#define YBLO  36224
#define H1HI  37376    // [2][16][136]
#define H1LO  41728
#define H2HI  46080
#define H2LO  50432
#define HROHI 54784    // [16][136]
#define HROLO 56960
// ---- f32 offsets (into sm) ----
#define FUP   29568    // [4][16][64]
#define FVP   33664    // [4][16][64]
#define FF1   37760    // [16][68]
#define FDW   38848    // [16][16][2]
#define FW0D  39360
#define FW0G  39488
#define FB1D  39616
#define FB1G  39744
#define FB2D  39872
#define FB2G  40000
#define FB3D  40128    // [64]
#define FRB1  40192    // [128]
#define FRB2  40320    // [32]
#define FTS   40352    // [128]
#define LDS_FLOATS 40480   // 161920 B

__device__ __forceinline__ float lipswish(float x) {
  return 0.909f * x / (1.0f + expf(-x));
}
__device__ __forceinline__ u32 bf16r(float x) {
  u32 u = __float_as_uint(x);
  return ((u + 0x7fffu + ((u >> 16) & 1u)) >> 16) & 0xffffu;
}
__device__ __forceinline__ void splitw(float x, u16& h, u16& l) {
  const u32 hb = bf16r(x);
  h = (u16)hb;
  l = (u16)bf16r(x - __uint_as_float(hb << 16));
}

// ---------------- prep: weight-norm + bf16 fragment pack (gW3 col-permuted) ----------------
__global__ void prep_kernel(const float* dr_v1, const float* dr_g1,
                            const float* dr_v2, const float* dr_g2,
                            const float* dr_v3, const float* dr_g3,
                            const float* di_v1, const float* di_g1,
                            const float* di_v2, const float* di_g2,
                            const float* di_v3, const float* di_g3,
                            const float* emb_W, const float* ro_W1, const float* ro_W2,
                            float* ws) {
  __shared__ float sred[2];
  u16* wsu = (u16*)ws;
  float* wsf = (float*)(wsu + U16_END);
  const int mat = blockIdx.y;
  const int row = blockIdx.x;
  const int i = threadIdx.x;
  const float* v = nullptr; const float* g = nullptr;
  int rows = 0, len = 0, O = 0; long F = -1; int l1 = 0; int w0 = 0;
  switch (mat) {
    case 0: v = dr_v1; g = dr_g1; rows = 128;  len = 65;  O = 128;  F = F_DW1; l1 = 1; w0 = FW_W0D; break;
    case 1: v = dr_v2; g = dr_g2; rows = 128;  len = 128; O = 128;  F = F_DW2; break;
    case 2: v = dr_v3; g = dr_g3; rows = 64;   len = 128; O = 64;   F = F_DW3; break;
    case 3: v = di_v1; g = di_g1; rows = 128;  len = 65;  O = 128;  F = F_GW1; l1 = 1; w0 = FW_W0G; break;
    case 4: v = di_v2; g = di_g2; rows = 128;  len = 128; O = 128;  F = F_GW2; break;
    case 5: v = di_v3; g = di_g3; rows = 1024; len = 128; O = 1024; F = F_GW3; break;
    case 6: v = emb_W; g = nullptr; rows = 64;  len = 64;  break;
    case 7: v = ro_W1; g = nullptr; rows = 128; len = 64;  O = 128; F = F_RO1; break;
    case 8: v = ro_W2; g = nullptr; rows = 32;  len = 128; O = 32;  F = F_RO2; break;
  }
  if (row >= rows) return;
  const float x = (i < len) ? v[(size_t)row * len + i] : 0.0f;
  float scale = 1.0f;
  if (g != nullptr) {
    float ss = x * x;
    #pragma unroll
    for (int d = 1; d < 64; d <<= 1) ss += __shfl_xor(ss, d);
    if ((i & 63) == 0) sred[i >> 6] = ss;
    __syncthreads();
    scale = g[row] / sqrtf(sred[0] + sred[1]);
  }
  const float xs = x * scale;
  if (mat == 6) {
    if (i < len) wsf[FW_EMB + i * 64 + row] = xs;
    return;
  }
  int ro = row;
  if (mat == 5) ro = ((row & 15) << 6) | (row >> 4);   // col permute: n*64 + l
  if (l1) {
    if (i == 0) wsf[w0 + row] = xs;
    if (i >= 1 && i < len) {
      const int kk = i - 1;
      wsu[F + ((size_t)((kk >> 3) * O + ro)) * 8 + (kk & 7)] = (u16)bf16r(xs);
    }
  } else if (i < len) {
    wsu[F + ((size_t)((i >> 3) * O + ro)) * 8 + (i & 7)] = (u16)bf16r(xs);
  }
}

__device__ __forceinline__ f32x4 mfma2(bf16x8 hi, bf16x8 lo, bf16x8 b, f32x4 acc) {
  acc = __builtin_amdgcn_mfma_f32_16x16x32_bf16(hi, b, acc, 0, 0, 0);
  acc = __builtin_amdgcn_mfma_f32_16x16x32_bf16(lo, b, acc, 0, 0, 0);
  return acc;
}
__device__ __forceinline__ bf16x8 ldfrag(const u16* p) { return *(const bf16x8*)p; }

// ---------------- main persistent kernel: 64 blocks x 1024 threads (16 waves), 16 rows ----------------
__global__ void __launch_bounds__(1024)
__attribute__((amdgpu_waves_per_eu(4, 4)))
sde_main(const float* __restrict__ init_noise, const float* __restrict__ bm,
         const float* __restrict__ ts_g, const int* __restrict__ p_steps,
         const int* __restrict__ p_mult, const float* __restrict__ emb_b,
         const float* __restrict__ dr_b1, const float* __restrict__ dr_b2, const float* __restrict__ dr_b3,
         const float* __restrict__ di_b1, const float* __restrict__ di_b2, const float* __restrict__ di_b3,
         const float* __restrict__ ro_b1, const float* __restrict__ ro_b2,
         const float* __restrict__ ws, float* __restrict__ out)
{
  extern __shared__ float sm[];
  u16* lu = (u16*)sm;

  const int t = threadIdx.x;
  const int b0 = blockIdx.x * NB;
  const u16* __restrict__ wsu = (const u16*)ws;
  const float* __restrict__ wsf = (const float*)(wsu + U16_END);
  const int steps = p_steps[0], mult = p_mult[0];

  // ---- stage W2 fragments into LDS (65536 B, contiguous from F_DW2) ----
  {
    float4* dst = (float4*)lu;
    const float4* src = (const float4*)(wsu + F_DW2);
    #pragma unroll 4
    for (int i = t; i < 4096; i += 1024) dst[i] = src[i];
  }
  // ---- stage constants ----
  {
    if (t < 128) { sm[FTS + t] = ts_g[t]; sm[FW0D + t] = wsf[FW_W0D + t]; sm[FW0G + t] = wsf[FW_W0G + t]; }
    else if (t < 256) { const int i = t - 128; sm[FB1D + i] = dr_b1[i]; sm[FB1G + i] = di_b1[i]; }
    else if (t < 384) { const int i = t - 256; sm[FB2D + i] = dr_b2[i]; sm[FB2G + i] = di_b2[i]; }
    else if (t < 512) { sm[FRB1 + t - 384] = ro_b1[t - 384]; }
    else if (t < 576) { sm[FB3D + t - 512] = dr_b3[t - 512]; }
    else if (t < 608) { sm[FRB2 + t - 576] = ro_b2[t - 576]; }
    if (t < 256) { float2 zz; zz.x = 0.f; zz.y = 0.f;
                   *(float2*)&sm[FDW + (t >> 4) * 32 + (t & 15) * 2] = zz; }
  }

  // ---- init: y0 = init_noise @ embT + emb_b; 1 state element per thread ----
  const int r_own = t >> 6;
  const int o_own = t & 63;
  float y_r, z_r, f_r = 0.f, v_r = 0.f;
  {
    const float* __restrict__ inr = init_noise + (size_t)(b0 + r_own) * 64;
    float a = emb_b[o_own];
    #pragma unroll 8
    for (int i = 0; i < 64; ++i) a = fmaf(inr[i], wsf[FW_EMB + i * 64 + o_own], a);
    y_r = a; z_r = a;
    u16 hh, ll; splitw(a, hh, ll);
    lu[ZHI + r_own * 72 + o_own] = hh;
    lu[ZLO + r_own * 72 + o_own] = ll;
    lu[YBHI + r_own * 72 + o_own] = hh;
    lu[YBLO + r_own * 72 + o_own] = ll;
  }

  const int w = t >> 6;          // wave 0..15
  const int lane = t & 63;
  const int g = lane >> 4;       // k-octet group
  const int c = lane & 15;       // A-row / col index
  const int netw = w >> 3;       // L1/L2: waves 0-7 drift, 8-15 diffusion
  const int nt = w & 7;
  const int col1 = nt * 16 + c;  // this wave's N-column for L1/L2
  const int nq = w >> 2;         // gW3 noise quarter (0..3)
  const int lt = w & 3;          // gW3 latent tile (0..3)

  // small per-wave weight fragments (loaded once; reload is cheap/batched)
  bf16x8 rw1[2];
  #pragma unroll
  for (int kt = 0; kt < 2; ++kt)
    rw1[kt] = ldfrag(wsu + (netw ? F_GW1 : F_DW1) + ((size_t)((kt * 4 + g) * 128 + col1)) * 8);
  bf16x8 rro1[2];
  if (w >= 8) {
    #pragma unroll
    for (int kt = 0; kt < 2; ++kt)
      rro1[kt] = ldfrag(wsu + F_RO1 + ((size_t)((kt * 4 + g) * 128 + (w - 8) * 16 + c)) * 8);
  }
  bf16x8 rd3[4];
  if (w < 4) {
    #pragma unroll
    for (int kt = 0; kt < 4; ++kt)
      rd3[kt] = ldfrag(wsu + F_DW3 + ((size_t)((kt * 4 + g) * 64 + w * 16 + c)) * 8);
  }
  bf16x8 rro2[4];
  if (w < 2) {
    #pragma unroll
    for (int kt = 0; kt < 4; ++kt)
      rro2[kt] = ldfrag(wsu + F_RO2 + ((size_t)((kt * 4 + g) * 32 + w * 16 + c)) * 8);
  }
  // gW3 bias values for this wave's (nq, lt) block — constant across steps
  float cb3[4];
  #pragma unroll
  for (int a = 0; a < 4; ++a)
    cb3[a] = di_b3[(lt * 16 + c) * 16 + (nq * 4 + a)];

  __syncthreads();

  #pragma unroll 1
  for (int k = 0; k < TT; ++k) {
    const float tval = sm[FTS + k];

    // ==== P1: L1 both nets (1 tile/wave) + ro1(y[k-1]) on waves 8-15 + noise rotate ====
    {
      bf16x8 zh[2], zl[2];
      #pragma unroll
      for (int kt = 0; kt < 2; ++kt) {
        zh[kt] = ldfrag(lu + ZHI + c * 72 + kt * 32 + g * 8);
        zl[kt] = ldfrag(lu + ZLO + c * 72 + kt * 32 + g * 8);
      }
      const float ci = netw ? fmaf(tval, sm[FW0G + col1], sm[FB1G + col1])
                            : fmaf(tval, sm[FW0D + col1], sm[FB1D + col1]);
      f32x4 acc = {ci, ci, ci, ci};
      #pragma unroll
      for (int kt = 0; kt < 2; ++kt) acc = mfma2(zh[kt], zl[kt], rw1[kt], acc);
      #pragma unroll
      for (int j = 0; j < 4; ++j) {
        u16 hh, ll; splitw(lipswish(acc[j]), hh, ll);
        lu[H1HI + netw * 2176 + (g * 4 + j) * 136 + col1] = hh;
        lu[H1LO + netw * 2176 + (g * 4 + j) * 136 + col1] = ll;
      }
      if (w >= 8 && k > 0) {     // readout stage 1, token k-1
        bf16x8 yh[2], yl[2];
        #pragma unroll
        for (int kt = 0; kt < 2; ++kt) {
          yh[kt] = ldfrag(lu + YBHI + c * 72 + kt * 32 + g * 8);
          yl[kt] = ldfrag(lu + YBLO + c * 72 + kt * 32 + g * 8);
        }
        const int colr = (w - 8) * 16 + c;
        const float cr = sm[FRB1 + colr];
        f32x4 ar = {cr, cr, cr, cr};
        #pragma unroll
        for (int kt = 0; kt < 2; ++kt) ar = mfma2(yh[kt], yl[kt], rro1[kt], ar);
        #pragma unroll
        for (int j = 0; j < 4; ++j) {
          u16 hh, ll; splitw(lipswish(ar[j]), hh, ll);
          lu[HROHI + (g * 4 + j) * 136 + colr] = hh;
          lu[HROLO + (g * 4 + j) * 136 + colr] = ll;
        }
      }
      if (t < 256) {             // rotate noise: dwi = old dwn; dwn = dw_k
        const int rr = t >> 4, nn = t & 15;
        const float old = sm[FDW + rr * 32 + nn * 2 + 1];
        float nv = 0.f;
        if (k < TT - 1)
          nv = bm[((size_t)k * NBATCH + b0 + rr) * 16 + nn] * sqrtf(sm[FTS + k + 1] - tval);
        float2 wv; wv.x = old; wv.y = nv;
        *(float2*)&sm[FDW + rr * 32 + nn * 2] = wv;
      }
    }
    __syncthreads();

    // ==== P2: L2 both nets (1 tile/wave, B from LDS) + ro2 -> out (waves 0-1) ====
    {
      bf16x8 ah[4], al[4];
      #pragma unroll
      for (int kt = 0; kt < 4; ++kt) {
        ah[kt] = ldfrag(lu + H1HI + netw * 2176 + c * 136 + kt * 32 + g * 8);
        al[kt] = ldfrag(lu + H1LO + netw * 2176 + c * 136 + kt * 32 + g * 8);
      }
      const float ci = netw ? sm[FB2G + col1] : sm[FB2D + col1];
      f32x4 acc = {ci, ci, ci, ci};
      #pragma unroll
      for (int kt = 0; kt < 4; ++kt) {
        const bf16x8 b = ldfrag(lu + LW2 + netw * 16384 + ((kt * 4 + g) * 128 + col1) * 8);
        acc = mfma2(ah[kt], al[kt], b, acc);
      }
      #pragma unroll
      for (int j = 0; j < 4; ++j) {
        u16 hh, ll; splitw(lipswish(acc[j]), hh, ll);
        lu[H2HI + netw * 2176 + (g * 4 + j) * 136 + col1] = hh;
        lu[H2LO + netw * 2176 + (g * 4 + j) * 136 + col1] = ll;
      }
      if (w < 2 && k > 0) {      // readout stage 2, token k-1
        bf16x8 hh4[4], hl4[4];
        #pragma unroll
        for (int kt = 0; kt < 4; ++kt) {
          hh4[kt] = ldfrag(lu + HROHI + c * 136 + kt * 32 + g * 8);
          hl4[kt] = ldfrag(lu + HROLO + c * 136 + kt * 32 + g * 8);
        }
        const int col = w * 16 + c;
        const float cr = sm[FRB2 + col];
        f32x4 ar = {cr, cr, cr, cr};
        #pragma unroll
        for (int kt = 0; kt < 4; ++kt) ar = mfma2(hh4[kt], hl4[kt], rro2[kt], ar);
        const int tg = k - 1;
        const int matched = (mult > 0 && (tg % mult) == 0) ? (tg / mult) : -1;
        #pragma unroll
        for (int j = 0; j < 4; ++j) {
          const int m = g * 4 + j;
          out[((size_t)(b0 + m) * TT + tg) * OUTD + col] = ar[j];
          if (matched >= 0 && matched < steps)
            out[(size_t)NBATCH * TT * OUTD + ((size_t)(b0 + m) * steps + matched) * OUTD + col] = ar[j];
        }
      }
    }
    __syncthreads();

    // ==== P3: dW3 (waves 0-3) + gW3 streamed with BATCHED loads + in-flight contraction ====
    {
      if (w < 4) {
        bf16x8 dh[4], dl[4];
        #pragma unroll
        for (int kt = 0; kt < 4; ++kt) {
          dh[kt] = ldfrag(lu + H2HI + c * 136 + kt * 32 + g * 8);
          dl[kt] = ldfrag(lu + H2LO + c * 136 + kt * 32 + g * 8);
        }
        const int col = w * 16 + c;
        const float ci = sm[FB3D + col];
        f32x4 acc = {ci, ci, ci, ci};
        #pragma unroll
        for (int kt = 0; kt < 4; ++kt) acc = mfma2(dh[kt], dl[kt], rd3[kt], acc);
        #pragma unroll
        for (int j = 0; j < 4; ++j) sm[FF1 + (g * 4 + j) * 68 + col] = acc[j];
      }
      bf16x8 gh[4], gl[4];
      #pragma unroll
      for (int kt = 0; kt < 4; ++kt) {
        gh[kt] = ldfrag(lu + H2HI + 2176 + c * 136 + kt * 32 + g * 8);
        gl[kt] = ldfrag(lu + H2LO + 2176 + c * 136 + kt * 32 + g * 8);
      }
      // batch-issue ALL 16 B-fragment loads (4 tiles x 4 k-frags) before any MFMA
      bf16x8 bfr[4][4];
      #pragma unroll
      for (int a = 0; a < 4; ++a) {
        const int colb = (nq * 4 + a) * 64 + lt * 16 + c;
        #pragma unroll
        for (int kt = 0; kt < 4; ++kt)
          bfr[a][kt] = ldfrag(wsu + F_GW3 + ((size_t)((kt * 4 + g) * 1024 + colb)) * 8);
      }
      f32x4 acc0 = {cb3[0], cb3[0], cb3[0], cb3[0]};
      f32x4 acc1 = {cb3[1], cb3[1], cb3[1], cb3[1]};
      f32x4 acc2 = {cb3[2], cb3[2], cb3[2], cb3[2]};
      f32x4 acc3 = {cb3[3], cb3[3], cb3[3], cb3[3]};
      #pragma unroll
      for (int kt = 0; kt < 4; ++kt) {   // 4 independent chains interleaved
        acc0 = __builtin_amdgcn_mfma_f32_16x16x32_bf16(gh[kt], bfr[0][kt], acc0, 0, 0, 0);
        acc1 = __builtin_amdgcn_mfma_f32_16x16x32_bf16(gh[kt], bfr[1][kt], acc1, 0, 0, 0);
        acc2 = __builtin_amdgcn_mfma_f32_16x16x32_bf16(gh[kt], bfr[2][kt], acc2, 0, 0, 0);
        acc3 = __builtin_amdgcn_mfma_f32_16x16x32_bf16(gh[kt], bfr[3][kt], acc3, 0, 0, 0);
        acc0 = __builtin_amdgcn_mfma_f32_16x16x32_bf16(gl[kt], bfr[0][kt], acc0, 0, 0, 0);
        acc1 = __builtin_amdgcn_mfma_f32_16x16x32_bf16(gl[kt], bfr[1][kt], acc1, 0, 0, 0);
        acc2 = __builtin_amdgcn_mfma_f32_16x16x32_bf16(gl[kt], bfr[2][kt], acc2, 0, 0, 0);
        acc3 = __builtin_amdgcn_mfma_f32_16x16x32_bf16(gl[kt], bfr[3][kt], acc3, 0, 0, 0);
      }
      float ua[4] = {0.f, 0.f, 0.f, 0.f}, va[4] = {0.f, 0.f, 0.f, 0.f};
      #pragma unroll
      for (int j = 0; j < 4; ++j) {
        const float2 dw0 = *(const float2*)&sm[FDW + (g * 4 + j) * 32 + (nq * 4 + 0) * 2];
        const float2 dw1 = *(const float2*)&sm[FDW + (g * 4 + j) * 32 + (nq * 4 + 1) * 2];
        const float2 dw2 = *(const float2*)&sm[FDW + (g * 4 + j) * 32 + (nq * 4 + 2) * 2];
        const float2 dw3 = *(const float2*)&sm[FDW + (g * 4 + j) * 32 + (nq * 4 + 3) * 2];
        ua[j] = fmaf(acc0[j], dw0.x, fmaf(acc1[j], dw1.x, fmaf(acc2[j], dw2.x, acc3[j] * dw3.x)));
        va[j] = fmaf(acc0[j], dw0.y, fmaf(acc1[j], dw1.y, fmaf(acc2[j], dw2.y, acc3[j] * dw3.y)));
      }
      #pragma unroll
      for (int j = 0; j < 4; ++j) {
        sm[FUP + nq * 1024 + (g * 4 + j) * 64 + lt * 16 + c] = ua[j];
        sm[FVP + nq * 1024 + (g * 4 + j) * 64 + lt * 16 + c] = va[j];
      }
    }
    __syncthreads();

    // ==== P4: Heun update, one element per thread ====
    {
      const float f1 = sm[FF1 + r_own * 68 + o_own];
      float u1 = 0.f, v1 = 0.f;
      #pragma unroll
      for (int q = 0; q < 4; ++q) {
        u1 += sm[FUP + q * 1024 + r_own * 64 + o_own];
        v1 += sm[FVP + q * 1024 + r_own * 64 + o_own];
      }
      const float dti = (k > 0) ? (tval - sm[FTS + k - 1]) : 0.f;
      const float dtn = (k < TT - 1) ? (sm[FTS + k + 1] - tval) : 0.f;
      y_r += 0.5f * (f_r + f1) * dti + 0.5f * (v_r + u1);
      z_r = 2.f * y_r - z_r + f1 * dtn + v1;
      f_r = f1; v_r = v1;
      u16 hh, ll;
      splitw(z_r, hh, ll);
      lu[ZHI + r_own * 72 + o_own] = hh;
      lu[ZLO + r_own * 72 + o_own] = ll;
      splitw(y_r, hh, ll);
      lu[YBHI + r_own * 72 + o_own] = hh;
      lu[YBLO + r_own * 72 + o_own] = ll;
    }
    __syncthreads();
  }

  // ==== tail: readout of token TT-1 ====
  if (w >= 8) {
    bf16x8 yh[2], yl[2];
    #pragma unroll
    for (int kt = 0; kt < 2; ++kt) {
      yh[kt] = ldfrag(lu + YBHI + c * 72 + kt * 32 + g * 8);
      yl[kt] = ldfrag(lu + YBLO + c * 72 + kt * 32 + g * 8);
    }
    const int colr = (w - 8) * 16 + c;
    const float cr = sm[FRB1 + colr];
    f32x4 ar = {cr, cr, cr, cr};
    #pragma unroll
    for (int kt = 0; kt < 2; ++kt) ar = mfma2(yh[kt], yl[kt], rro1[kt], ar);
    #pragma unroll
    for (int j = 0; j < 4; ++j) {
      u16 hh, ll; splitw(lipswish(ar[j]), hh, ll);
      lu[HROHI + (g * 4 + j) * 136 + colr] = hh;
      lu[HROLO + (g * 4 + j) * 136 + colr] = ll;
    }
  }
  __syncthreads();
  if (w < 2) {
    bf16x8 hh4[4], hl4[4];
    #pragma unroll
    for (int kt = 0; kt < 4; ++kt) {
      hh4[kt] = ldfrag(lu + HROHI + c * 136 + kt * 32 + g * 8);
      hl4[kt] = ldfrag(lu + HROLO + c * 136 + kt * 32 + g * 8);
    }
    const int col = w * 16 + c;
    const float cr = sm[FRB2 + col];
    f32x4 ar = {cr, cr, cr, cr};
    #pragma unroll
    for (int kt = 0; kt < 4; ++kt) ar = mfma2(hh4[kt], hl4[kt], rro2[kt], ar);
    const int tg = TT - 1;
    const int matched = (mult > 0 && (tg % mult) == 0) ? (tg / mult) : -1;
    #pragma unroll
    for (int j = 0; j < 4; ++j) {
      const int m = g * 4 + j;
      out[((size_t)(b0 + m) * TT + tg) * OUTD + col] = ar[j];
      if (matched >= 0 && matched < steps)
        out[(size_t)NBATCH * TT * OUTD + ((size_t)(b0 + m) * steps + matched) * OUTD + col] = ar[j];
    }
  }
}

extern "C" void kernel_launch(void* const* d_in, const int* in_sizes, int n_in,
                              void* d_out, int out_size, void* d_ws, size_t ws_size,
                              hipStream_t stream) {
  (void)in_sizes; (void)n_in; (void)out_size; (void)ws_size;
  const float* init_noise = (const float*)d_in[0];
  const float* bm_noise   = (const float*)d_in[1];
  const float* ts         = (const float*)d_in[2];
  const int*   p_steps    = (const int*)d_in[3];
  const int*   p_mult     = (const int*)d_in[4];
  const float* emb_W = (const float*)d_in[5];
  const float* emb_b = (const float*)d_in[6];
  const float* dr_v1 = (const float*)d_in[7];
  const float* dr_g1 = (const float*)d_in[8];
  const float* dr_b1 = (const float*)d_in[9];
  const float* dr_v2 = (const float*)d_in[10];
  const float* dr_g2 = (const float*)d_in[11];
  const float* dr_b2 = (const float*)d_in[12];
  const float* dr_v3 = (const float*)d_in[13];
  const float* dr_g3 = (const float*)d_in[14];
  const float* dr_b3 = (const float*)d_in[15];
  const float* di_v1 = (const float*)d_in[16];
  const float* di_g1 = (const float*)d_in[17];
  const float* di_b1 = (const float*)d_in[18];
  const float* di_v2 = (const float*)d_in[19];
  const float* di_g2 = (const float*)d_in[20];
  const float* di_b2 = (const float*)d_in[21];
  const float* di_v3 = (const float*)d_in[22];
  const float* di_g3 = (const float*)d_in[23];
  const float* di_b3 = (const float*)d_in[24];
  const float* ro_W1 = (const float*)d_in[25];
  const float* ro_b1 = (const float*)d_in[26];
  const float* ro_W2 = (const float*)d_in[27];
  const float* ro_b2 = (const float*)d_in[28];
  float* ws = (float*)d_ws;
  float* out = (float*)d_out;

  (void)hipFuncSetAttribute((const void*)sde_main,
                            hipFuncAttributeMaxDynamicSharedMemorySize, 160 * 1024);

  prep_kernel<<<dim3(1024, 9), 128, 0, stream>>>(
      dr_v1, dr_g1, dr_v2, dr_g2, dr_v3, dr_g3,
      di_v1, di_g1, di_v2, di_g2, di_v3, di_g3,
      emb_W, ro_W1, ro_W2, ws);

  sde_main<<<NBLK, 1024, LDS_FLOATS * 4, stream>>>(
      init_noise, bm_noise, ts, p_steps, p_mult,
      emb_b, dr_b1, dr_b2, dr_b3, di_b1, di_b2, di_b3,
      ro_b1, ro_b2, ws, out);
}